// Round 6
// baseline (59.299 us; speedup 1.0000x reference)
//
#include <hip/hip_runtime.h>
#include <stdint.h>

#define IMG  512
#define CPT  8
#define CGRP (IMG / CPT)    // 64 col-groups per row

typedef float    v2f   __attribute__((ext_vector_type(2)));
typedef _Float16 h2    __attribute__((ext_vector_type(2)));
typedef __fp16   f16x2 __attribute__((ext_vector_type(2)));

#define SCALE 2.8853900817779268f   // 2*log2(e), folded into W and bias

static __device__ __forceinline__ h2 pkrtz(float a, float b) {
    f16x2 t = __builtin_amdgcn_cvt_pkrtz(a, b);   // v_cvt_pkrtz_f16_f32
    return __builtin_bit_cast(h2, t);
}

#if __has_builtin(__builtin_amdgcn_fdot2)
#define FDOT2(a, b, c) __builtin_amdgcn_fdot2((a), (b), (c), false)
#else
static __device__ __forceinline__ float fdot2_sw(h2 a, h2 b, float c) {
    return fmaf((float)a.x, (float)b.x, fmaf((float)a.y, (float)b.y, c));
}
#define FDOT2(a, b, c) fdot2_sw((a), (b), (c))
#endif

// ws layout (dwords): [0..35] u32 half2 weight pairs u[c][k] (scaled);
//                     [36..44] w8[c] f32 (scaled); [45..53] bv[c] f32 (scaled)
__global__ void prepack_kernel(const float* __restrict__ W,
                               const float* __restrict__ B,
                               uint32_t* __restrict__ ws) {
    int c = threadIdx.x;
    if (c < 9) {
        const float* wc = W + c * 9;
#pragma unroll
        for (int k = 0; k < 4; ++k) {
            h2 t = pkrtz(wc[2 * k] * SCALE, wc[2 * k + 1] * SCALE);
            ws[c * 4 + k] = __builtin_bit_cast(uint32_t, t);
        }
        ((float*)ws)[36 + c] = wc[8] * SCALE;
        ((float*)ws)[45 + c] = B[c] * SCALE;
    }
}

struct Rows { float r0[10], r1[10], r2[10]; };

__global__ __launch_bounds__(256, 4) void fused_convtap_kernel(
    const float* __restrict__ x,       // (B,1,512,512)
    const uint32_t* __restrict__ wsu,  // prepacked weights
    float* __restrict__ out)           // (B,1,512,512)
{
    const float* w8v = (const float*)(wsu + 36);
    const float* bvv = (const float*)(wsu + 45);

    const int tid = blockIdx.x * 256 + threadIdx.x;
    const int xg  = tid & (CGRP - 1);
    const int row = tid >> 6;            // tile0: b in 0..15; tile1: +8192
    const int y   = row & (IMG - 1);     // same y for both tiles
    const int x0  = xg * CPT;

    const size_t tile_off = (size_t)8192 * IMG;   // 16 batches of rows
    const float* xr0 = x + (size_t)row * IMG;
    const float* xr1 = xr0 + tile_off;

    const bool has_l = (x0 > 0);
    const bool has_r = (x0 < IMG - CPT);
    const bool has_t = (y > 0);
    const bool has_b = (y < IMG - 1);

    auto load_row = [&](const float* p, float* r) {
        float4 a = *reinterpret_cast<const float4*>(p + x0);
        float4 c = *reinterpret_cast<const float4*>(p + x0 + 4);
        r[1] = a.x; r[2] = a.y; r[3] = a.z; r[4] = a.w;
        r[5] = c.x; r[6] = c.y; r[7] = c.z; r[8] = c.w;
        r[0] = has_l ? p[x0 - 1] : 0.0f;
        r[9] = has_r ? p[x0 + 8] : 0.0f;
    };
    auto zero_row = [&](float* r) {
#pragma unroll
        for (int k = 0; k < 10; ++k) r[k] = 0.0f;
    };

    // Issue ALL loads (both tiles) before any compute: tile1's HBM latency
    // hides under tile0's compute. __restrict__ lets these hoist over stores.
    Rows ra, rb;
    if (has_t) load_row(xr0 - IMG, ra.r0); else zero_row(ra.r0);
               load_row(xr0,       ra.r1);
    if (has_b) load_row(xr0 + IMG, ra.r2); else zero_row(ra.r2);
    if (has_t) load_row(xr1 - IMG, rb.r0); else zero_row(rb.r0);
               load_row(xr1,       rb.r1);
    if (has_b) load_row(xr1 + IMG, rb.r2); else zero_row(rb.r2);

    // Uniform prepacked weights -> SGPRs.
    h2 u[9][4];
#pragma unroll
    for (int c = 0; c < 9; ++c)
#pragma unroll
        for (int k = 0; k < 4; ++k)
            u[c][k] = __builtin_bit_cast(h2, wsu[c * 4 + k]);
    float w8[9], bv[9];
#pragma unroll
    for (int c = 0; c < 9; ++c) { w8[c] = w8v[c]; bv[c] = bvv[c]; }

    auto compute_tile = [&](const Rows& R, float* orow) {
        const float* r0 = R.r0;
        const float* r1 = R.r1;
        const float* r2 = R.r2;
        float o[CPT];
#pragma unroll
        for (int tp = 0; tp < 4; ++tp) {
            const int t0 = 2 * tp;
            // f16 K-pairs, pixels t0/t0+1:
            // A=(p0q0,p0q1) B=(p0q2,p1q0) C=(p1q1,p1q2) D=(p2q0,p2q1), lone p2q2 f32
            h2 A0 = pkrtz(r0[t0],     r0[t0 + 1]);
            h2 B0 = pkrtz(r0[t0 + 2], r1[t0]);
            h2 C0 = pkrtz(r1[t0 + 1], r1[t0 + 2]);
            h2 D0 = pkrtz(r2[t0],     r2[t0 + 1]);
            h2 A1 = pkrtz(r0[t0 + 1], r0[t0 + 2]);
            h2 B1 = pkrtz(r0[t0 + 3], r1[t0 + 1]);
            h2 C1 = pkrtz(r1[t0 + 2], r1[t0 + 3]);
            h2 D1 = pkrtz(r2[t0 + 1], r2[t0 + 2]);

            v2f acc = {0.0f, 0.0f};
#pragma unroll
            for (int c = 0; c < 9; ++c) {
                float fx = bv[c], fy = bv[c];
                fx = FDOT2(A0, u[c][0], fx);
                fx = FDOT2(B0, u[c][1], fx);
                fx = FDOT2(C0, u[c][2], fx);
                fx = FDOT2(D0, u[c][3], fx);
                fx = fmaf(r2[t0 + 2], w8[c], fx);
                fy = FDOT2(A1, u[c][0], fy);
                fy = FDOT2(B1, u[c][1], fy);
                fy = FDOT2(C1, u[c][2], fy);
                fy = FDOT2(D1, u[c][3], fy);
                fy = fmaf(r2[t0 + 3], w8[c], fy);

                // tanh(fc) = 1 - 2/(exp2(fc*2log2e)+1); scale folded into W,b.
                v2f e   = { __builtin_amdgcn_exp2f(fx), __builtin_amdgcn_exp2f(fy) };
                v2f ep1 = e + (v2f){1.0f, 1.0f};
                v2f rr  = { __builtin_amdgcn_rcpf(ep1.x), __builtin_amdgcn_rcpf(ep1.y) };
                v2f th  = __builtin_elementwise_fma((v2f){-2.0f, -2.0f}, rr,
                                                    (v2f){1.0f, 1.0f});

                const int i = c / 3, j = c - 3 * i;
                const float* rj = (j == 0) ? r0 : (j == 1) ? r1 : r2;
                v2f px2 = { rj[t0 + i], rj[t0 + 1 + i] };
                acc = __builtin_elementwise_fma(px2, th, acc);
            }
            o[t0] = acc.x; o[t0 + 1] = acc.y;
        }
        *reinterpret_cast<float4*>(orow)     = make_float4(o[0], o[1], o[2], o[3]);
        *reinterpret_cast<float4*>(orow + 4) = make_float4(o[4], o[5], o[6], o[7]);
    };

    float* orow0 = out + (size_t)row * IMG + x0;
    compute_tile(ra, orow0);
    compute_tile(rb, orow0 + tile_off);
}

extern "C" void kernel_launch(void* const* d_in, const int* in_sizes, int n_in,
                              void* d_out, int out_size, void* d_ws, size_t ws_size,
                              hipStream_t stream) {
    const float* x  = (const float*)d_in[0];   // (B,1,512,512) f32
    const float* W  = (const float*)d_in[1];   // (9,1,3,3)     f32
    const float* Bv = (const float*)d_in[2];   // (9,)          f32
    float* out = (float*)d_out;
    uint32_t* ws = (uint32_t*)d_ws;

    prepack_kernel<<<1, 64, 0, stream>>>(W, Bv, ws);

    const int batch   = in_sizes[0] / (IMG * IMG);   // 32
    const int threads = batch * IMG * CGRP / 2;      // 524288 (2 tiles/thread)
    const int grid    = threads / 256;               // 2048
    fused_convtap_kernel<<<grid, 256, 0, stream>>>(x, ws, out);
}

// Round 7
// 39.817 us; speedup vs baseline: 1.4893x; 1.4893x over previous
//
#include <hip/hip_runtime.h>
#include <stdint.h>

#define IMG  512
#define CPT  8
#define CGRP (IMG / CPT)    // 64 col-groups per row

typedef float    v2f   __attribute__((ext_vector_type(2)));
typedef _Float16 h2    __attribute__((ext_vector_type(2)));
typedef __fp16   f16x2 __attribute__((ext_vector_type(2)));

#define SCALE 2.8853900817779268f   // 2*log2(e), folded into W and bias

static __device__ __forceinline__ h2 pkrtz(float a, float b) {
    f16x2 t = __builtin_amdgcn_cvt_pkrtz(a, b);   // v_cvt_pkrtz_f16_f32
    return __builtin_bit_cast(h2, t);
}

#if __has_builtin(__builtin_amdgcn_fdot2)
#define FDOT2(a, b, c) __builtin_amdgcn_fdot2((a), (b), (c), false)
#else
static __device__ __forceinline__ float fdot2_sw(h2 a, h2 b, float c) {
    return fmaf((float)a.x, (float)b.x, fmaf((float)a.y, (float)b.y, c));
}
#define FDOT2(a, b, c) fdot2_sw((a), (b), (c))
#endif

// ws layout (dwords): [0..35] u32 half2 weight pairs u[c][k] (scaled);
//                     [36..44] w8[c] f32 (scaled); [45..53] bv[c] f32 (scaled)
__global__ void prepack_kernel(const float* __restrict__ W,
                               const float* __restrict__ B,
                               uint32_t* __restrict__ ws) {
    int c = threadIdx.x;
    if (c < 9) {
        const float* wc = W + c * 9;
#pragma unroll
        for (int k = 0; k < 4; ++k) {
            h2 t = pkrtz(wc[2 * k] * SCALE, wc[2 * k + 1] * SCALE);
            ws[c * 4 + k] = __builtin_bit_cast(uint32_t, t);
        }
        ((float*)ws)[36 + c] = wc[8] * SCALE;
        ((float*)ws)[45 + c] = B[c] * SCALE;
    }
}

// Compute one 8-pixel tile. Array REFERENCES (no pointer decay) + value-level
// row selection with compile-time constants -> fully register-resident (SROA).
__device__ __forceinline__ void compute_tile(
    const float (&r0)[10], const float (&r1)[10], const float (&r2)[10],
    const h2 (&u)[9][4], const float (&w8)[9], const float (&bv)[9],
    float* __restrict__ orow)
{
#define RSEL(j, idx) ((j) == 0 ? r0[idx] : (j) == 1 ? r1[idx] : r2[idx])
    float o[CPT];
#pragma unroll
    for (int tp = 0; tp < 4; ++tp) {
        const int t0 = 2 * tp;
        // f16 K-pairs, pixels t0/t0+1:
        // A=(p0q0,p0q1) B=(p0q2,p1q0) C=(p1q1,p1q2) D=(p2q0,p2q1), lone p2q2 f32
        h2 A0 = pkrtz(r0[t0],     r0[t0 + 1]);
        h2 B0 = pkrtz(r0[t0 + 2], r1[t0]);
        h2 C0 = pkrtz(r1[t0 + 1], r1[t0 + 2]);
        h2 D0 = pkrtz(r2[t0],     r2[t0 + 1]);
        h2 A1 = pkrtz(r0[t0 + 1], r0[t0 + 2]);
        h2 B1 = pkrtz(r0[t0 + 3], r1[t0 + 1]);
        h2 C1 = pkrtz(r1[t0 + 2], r1[t0 + 3]);
        h2 D1 = pkrtz(r2[t0 + 1], r2[t0 + 2]);

        v2f acc = {0.0f, 0.0f};
#pragma unroll
        for (int c = 0; c < 9; ++c) {
            float fx = bv[c], fy = bv[c];
            fx = FDOT2(A0, u[c][0], fx);
            fx = FDOT2(B0, u[c][1], fx);
            fx = FDOT2(C0, u[c][2], fx);
            fx = FDOT2(D0, u[c][3], fx);
            fx = fmaf(r2[t0 + 2], w8[c], fx);
            fy = FDOT2(A1, u[c][0], fy);
            fy = FDOT2(B1, u[c][1], fy);
            fy = FDOT2(C1, u[c][2], fy);
            fy = FDOT2(D1, u[c][3], fy);
            fy = fmaf(r2[t0 + 3], w8[c], fy);

            // tanh(fc) = 1 - 2/(exp2(fc*2log2e)+1); scale folded into W,b.
            v2f e   = { __builtin_amdgcn_exp2f(fx), __builtin_amdgcn_exp2f(fy) };
            v2f ep1 = e + (v2f){1.0f, 1.0f};
            v2f rr  = { __builtin_amdgcn_rcpf(ep1.x), __builtin_amdgcn_rcpf(ep1.y) };
            v2f th  = __builtin_elementwise_fma((v2f){-2.0f, -2.0f}, rr,
                                                (v2f){1.0f, 1.0f});

            const int i = c / 3, j = c - 3 * i;
            v2f px2 = { RSEL(j, t0 + i), RSEL(j, t0 + 1 + i) };
            acc = __builtin_elementwise_fma(px2, th, acc);
        }
        o[t0] = acc.x; o[t0 + 1] = acc.y;
    }
#undef RSEL
    *reinterpret_cast<float4*>(orow)     = make_float4(o[0], o[1], o[2], o[3]);
    *reinterpret_cast<float4*>(orow + 4) = make_float4(o[4], o[5], o[6], o[7]);
}

__global__ __launch_bounds__(256) void fused_convtap_kernel(
    const float* __restrict__ x,       // (B,1,512,512)
    const uint32_t* __restrict__ wsu,  // prepacked weights
    float* __restrict__ out)           // (B,1,512,512)
{
    const float* w8v = (const float*)(wsu + 36);
    const float* bvv = (const float*)(wsu + 45);

    const int tid = blockIdx.x * 256 + threadIdx.x;
    const int xg  = tid & (CGRP - 1);
    const int row = tid >> 6;            // tile0: b in 0..15; tile1: +8192
    const int y   = row & (IMG - 1);     // same y for both tiles
    const int x0  = xg * CPT;

    const size_t tile_off = (size_t)8192 * IMG;   // 16 batches of rows
    const float* xr0 = x + (size_t)row * IMG;
    const float* xr1 = xr0 + tile_off;

    const bool has_l = (x0 > 0);
    const bool has_r = (x0 < IMG - CPT);
    const bool has_t = (y > 0);
    const bool has_b = (y < IMG - 1);

    auto load_row = [&](const float* p, float* r) {
        float4 a = *reinterpret_cast<const float4*>(p + x0);
        float4 c = *reinterpret_cast<const float4*>(p + x0 + 4);
        r[1] = a.x; r[2] = a.y; r[3] = a.z; r[4] = a.w;
        r[5] = c.x; r[6] = c.y; r[7] = c.z; r[8] = c.w;
        r[0] = has_l ? p[x0 - 1] : 0.0f;
        r[9] = has_r ? p[x0 + 8] : 0.0f;
    };
    auto zero_row = [&](float* r) {
#pragma unroll
        for (int k = 0; k < 10; ++k) r[k] = 0.0f;
    };

    // Named local arrays (no struct, no pointer reads in compute):
    float a0[10], a1[10], a2[10], b0[10], b1[10], b2[10];

    // Issue ALL loads (both tiles) before any compute: tile1's HBM latency
    // hides under tile0's compute.
    if (has_t) load_row(xr0 - IMG, a0); else zero_row(a0);
               load_row(xr0,       a1);
    if (has_b) load_row(xr0 + IMG, a2); else zero_row(a2);
    if (has_t) load_row(xr1 - IMG, b0); else zero_row(b0);
               load_row(xr1,       b1);
    if (has_b) load_row(xr1 + IMG, b2); else zero_row(b2);

    // Uniform prepacked weights -> SGPRs.
    h2 u[9][4];
#pragma unroll
    for (int c = 0; c < 9; ++c)
#pragma unroll
        for (int k = 0; k < 4; ++k)
            u[c][k] = __builtin_bit_cast(h2, wsu[c * 4 + k]);
    float w8[9], bv[9];
#pragma unroll
    for (int c = 0; c < 9; ++c) { w8[c] = w8v[c]; bv[c] = bvv[c]; }

    float* orow0 = out + (size_t)row * IMG + x0;
    compute_tile(a0, a1, a2, u, w8, bv, orow0);
    compute_tile(b0, b1, b2, u, w8, bv, orow0 + tile_off);
}

extern "C" void kernel_launch(void* const* d_in, const int* in_sizes, int n_in,
                              void* d_out, int out_size, void* d_ws, size_t ws_size,
                              hipStream_t stream) {
    const float* x  = (const float*)d_in[0];   // (B,1,512,512) f32
    const float* W  = (const float*)d_in[1];   // (9,1,3,3)     f32
    const float* Bv = (const float*)d_in[2];   // (9,)          f32
    float* out = (float*)d_out;
    uint32_t* ws = (uint32_t*)d_ws;

    prepack_kernel<<<1, 64, 0, stream>>>(W, Bv, ws);

    const int batch   = in_sizes[0] / (IMG * IMG);   // 32
    const int threads = batch * IMG * CGRP / 2;      // 524288 (2 tiles/thread)
    const int grid    = threads / 256;               // 2048
    fused_convtap_kernel<<<grid, 256, 0, stream>>>(x, ws, out);
}